// Round 12
// baseline (217.074 us; speedup 1.0000x reference)
//
#include <hip/hip_runtime.h>
#include <hip/hip_fp16.h>
#include <math.h>

#define NN 50000
#define EE 800000
#define E2 (EE + NN)
#define FIN 128
#define HC 256
#define HID 128
#define NCLS 10
#define NEG 0.2f
#define NB2 196          // buckets of 256 nodes
#define NBLK 256         // edge-partition blocks
#define WPART ((E2 + NBLK - 1) / NBLK)

typedef _Float16 f16x8 __attribute__((ext_vector_type(8)));
typedef float f32x4 __attribute__((ext_vector_type(4)));

#define FMA_MIX_LO(acc, u, w) \
    asm("v_fma_mix_f32 %0, %1, %2, %0 op_sel:[0,0,0] op_sel_hi:[1,0,0]" \
        : "+v"(acc) : "v"(u), "v"(w))
#define FMA_MIX_HI(acc, u, w) \
    asm("v_fma_mix_f32 %0, %1, %2, %0 op_sel:[1,0,0] op_sel_hi:[1,0,0]" \
        : "+v"(acc) : "v"(u), "v"(w))

__device__ inline uint pack2h(float a, float b) {
    return (uint)__half_as_ushort(__float2half(a)) |
           ((uint)__half_as_ushort(__float2half(b)) << 16);
}

// ---- prep: wgt[256][128], wct[128][256] fp16 transposed; vs/vd[128] float4 (folded att) ----
__global__ __launch_bounds__(256) void prep_kernel(const float* __restrict__ Wg,
                                                   const float* __restrict__ Wc,
                                                   const float* __restrict__ att_s,
                                                   const float* __restrict__ att_d,
                                                   ushort* __restrict__ wgt,
                                                   ushort* __restrict__ wct,
                                                   float4* __restrict__ vs,
                                                   float4* __restrict__ vd) {
    int i = blockIdx.x * 256 + threadIdx.x;
    if (i < HC * FIN) {
        int c = i & 255, k = i >> 8;
        wgt[c * FIN + k] = __half_as_ushort(__float2half(Wg[i]));
        int c2 = i & 127, k2 = i >> 7;
        wct[c2 * HC + k2] = __half_as_ushort(__float2half(Wc[i]));
    }
    if (blockIdx.x == 0 && threadIdx.x < FIN) {
        int k = threadIdx.x;
        float s[4] = {0.f, 0.f, 0.f, 0.f}, d[4] = {0.f, 0.f, 0.f, 0.f};
        for (int h = 0; h < 4; ++h)
            for (int c = 0; c < 64; ++c) {
                float wv = Wg[k * HC + h * 64 + c];
                s[h] += wv * att_s[h * 64 + c];
                d[h] += wv * att_d[h * 64 + c];
            }
        vs[k] = make_float4(s[0], s[1], s[2], s[3]);
        vd[k] = make_float4(d[0], d[1], d[2], d[3]);
    }
}

// ---- prep_x: x -> fp16 cast + a_s/a_d = x @ vs/vd ----
__global__ __launch_bounds__(256) void prep_x(const float* __restrict__ x,
                                              const float4* __restrict__ vs,
                                              const float4* __restrict__ vd,
                                              ushort* __restrict__ x_half,
                                              float* __restrict__ a_s,
                                              float* __restrict__ a_d) {
    const int node = blockIdx.x * 4 + (threadIdx.x >> 6);
    const int lane = threadIdx.x & 63;
    if (node >= NN) return;
    float2 xv = ((const float2*)(x + (size_t)node * FIN))[lane];
    ((uint*)x_half)[(size_t)node * 64 + lane] = pack2h(xv.x, xv.y);
    float4 v0 = vs[2 * lane], v1 = vs[2 * lane + 1];
    float4 d0 = vd[2 * lane], d1 = vd[2 * lane + 1];
    float ps0 = xv.x * v0.x + xv.y * v1.x;
    float ps1 = xv.x * v0.y + xv.y * v1.y;
    float ps2 = xv.x * v0.z + xv.y * v1.z;
    float ps3 = xv.x * v0.w + xv.y * v1.w;
    float pd0 = xv.x * d0.x + xv.y * d1.x;
    float pd1 = xv.x * d0.y + xv.y * d1.y;
    float pd2 = xv.x * d0.z + xv.y * d1.z;
    float pd3 = xv.x * d0.w + xv.y * d1.w;
#pragma unroll
    for (int m = 32; m >= 1; m >>= 1) {
        ps0 += __shfl_xor(ps0, m, 64); ps1 += __shfl_xor(ps1, m, 64);
        ps2 += __shfl_xor(ps2, m, 64); ps3 += __shfl_xor(ps3, m, 64);
        pd0 += __shfl_xor(pd0, m, 64); pd1 += __shfl_xor(pd1, m, 64);
        pd2 += __shfl_xor(pd2, m, 64); pd3 += __shfl_xor(pd3, m, 64);
    }
    if (lane == 0) {
        ((float4*)a_s)[node] = make_float4(ps0, ps1, ps2, ps3);
        ((float4*)a_d)[node] = make_float4(pd0, pd1, pd2, pd3);
    }
}

// ================= CSR build: bucketed, no global atomics =================
__global__ __launch_bounds__(256) void hist_coarse(const int* __restrict__ ei,
                                                   uint* __restrict__ blockhist) {
    __shared__ uint h[NB2];
    for (int i = threadIdx.x; i < NB2; i += 256) h[i] = 0;
    __syncthreads();
    int e0 = blockIdx.x * WPART, e1 = min(E2, e0 + WPART);
    for (int e = e0 + threadIdx.x; e < e1; e += 256) {
        int dst = (e < EE) ? ei[EE + e] : e - EE;
        atomicAdd(&h[dst >> 8], 1u);
    }
    __syncthreads();
    for (int i = threadIdx.x; i < NB2; i += 256) blockhist[i * NBLK + blockIdx.x] = h[i];
}

__global__ __launch_bounds__(256) void scan_blocks(const uint* __restrict__ blockhist,
                                                   uint* __restrict__ blockoff,
                                                   uint* __restrict__ total) {
    __shared__ uint sh[256];
    int b = blockIdx.x, t = threadIdx.x;
    uint v = blockhist[b * NBLK + t];
    sh[t] = v;
    __syncthreads();
#pragma unroll
    for (int off = 1; off < 256; off <<= 1) {
        uint y = (t >= off) ? sh[t - off] : 0;
        __syncthreads();
        sh[t] += y;
        __syncthreads();
    }
    blockoff[b * NBLK + t] = sh[t] - v;
    if (t == 255) total[b] = sh[255];
}

// reorder: local scan of total[] gives bucket bases (scan_buckets folded in)
__global__ __launch_bounds__(256) void reorder_kernel(const int* __restrict__ ei,
                                                      const uint* __restrict__ blockoff,
                                                      const uint* __restrict__ total,
                                                      uint* __restrict__ ebuf) {
    __shared__ uint sh[256];
    __shared__ uint cur[NB2];
    int t = threadIdx.x;
    uint v = (t < NB2) ? total[t] : 0;
    sh[t] = v;
    __syncthreads();
#pragma unroll
    for (int off = 1; off < 256; off <<= 1) {
        uint y = (t >= off) ? sh[t - off] : 0;
        __syncthreads();
        sh[t] += y;
        __syncthreads();
    }
    if (t < NB2) cur[t] = (sh[t] - v) + blockoff[t * NBLK + blockIdx.x];
    __syncthreads();
    int e0 = blockIdx.x * WPART, e1 = min(E2, e0 + WPART);
    for (int e = e0 + t; e < e1; e += 256) {
        int src, dst;
        if (e < EE) { src = ei[e]; dst = ei[EE + e]; }
        else        { src = dst = e - EE; }
        uint p = atomicAdd(&cur[dst >> 8], 1u);
        ebuf[p] = (uint)src | ((uint)(dst & 255) << 16);
    }
}

// per-bucket finalize: local scan of total[] gives this bucket's base/end
__global__ __launch_bounds__(256) void bucket_csr(const uint* __restrict__ ebuf,
                                                  const uint* __restrict__ total,
                                                  int* __restrict__ row_start,
                                                  float* __restrict__ dinv,
                                                  ushort* __restrict__ csr_src) {
    __shared__ uint ldeg[256], lcur[256], sh[256];
    __shared__ uint sbe[2];
    const int b = blockIdx.x, t = threadIdx.x;
    uint v = (t < NB2) ? total[t] : 0;
    sh[t] = v;
    __syncthreads();
#pragma unroll
    for (int off = 1; off < 256; off <<= 1) {
        uint y = (t >= off) ? sh[t - off] : 0;
        __syncthreads();
        sh[t] += y;
        __syncthreads();
    }
    if (t == b) { sbe[0] = sh[t] - v; sbe[1] = sh[t]; }
    ldeg[t] = 0;
    __syncthreads();
    const uint base = sbe[0], end = sbe[1];
    for (uint i = base + t; i < end; i += 256) atomicAdd(&ldeg[ebuf[i] >> 16], 1u);
    __syncthreads();
    uint dv = ldeg[t];
    sh[t] = dv;
    __syncthreads();
#pragma unroll
    for (int off = 1; off < 256; off <<= 1) {
        uint y = (t >= off) ? sh[t - off] : 0;
        __syncthreads();
        sh[t] += y;
        __syncthreads();
    }
    uint lscan = sh[t] - dv;
    int node = b * 256 + t;
    if (node < NN) {
        row_start[node] = (int)(base + lscan);
        dinv[node] = rsqrtf((float)dv);
    }
    lcur[t] = base + lscan;
    __syncthreads();
    for (uint i = base + t; i < end; i += 256) {
        uint pk = ebuf[i];
        uint p = atomicAdd(&lcur[pk >> 16], 1u);
        csr_src[p] = (ushort)(pk & 0xFFFFu);
    }
    if (b == 0 && t == 0) row_start[NN] = E2;
}

// ==== fused: gather(x) -> y(LDS) -> proj MFMA -> ELU xg(LDS) -> gemm2 MFMA -> xw ====
// block = 16 nodes, 4 waves; wave w gathers nodes 4w..4w+3, then does head w (proj)
// and cols [32w,32w+32) (gemm2).
__global__ __launch_bounds__(256) void gat_fused(const ushort* __restrict__ x_half,
                                                 const float* __restrict__ a_s,
                                                 const float* __restrict__ a_d,
                                                 const int* __restrict__ row_start,
                                                 const ushort* __restrict__ csr_src,
                                                 const ushort* __restrict__ wgt,
                                                 const float* __restrict__ bg,
                                                 const ushort* __restrict__ wct,
                                                 ushort* __restrict__ xw) {
    __shared__ ushort yt[16][520];    // y-tile: [node][head*128+k], +8 pad
    __shared__ ushort xt[16][264];    // xg-tile
    __shared__ ushort xt2[16][136];   // xw-tile staging
    __shared__ int    lds_off[4][64];
    __shared__ float4 lds_ex[4][64];

    const int t = threadIdx.x;
    const int w = t >> 6;
    const int lane = t & 63;
    const int lr = lane & 15;
    const int lg = lane >> 4;
    const int rowbase = blockIdx.x * 16;

    const char* xbase = (const char*)x_half;
    const uint lane4 = (uint)lane * 4;

    // ---------- Phase A: gather 4 nodes ----------
    for (int i = 0; i < 4; ++i) {
        const int nl = 4 * w + i;
        const int node = rowbase + nl;
        const int s0 = row_start[node], s1 = row_start[node + 1];
        const float4 ad = ((const float4*)a_d)[node];

        float den0 = 0.f, den1 = 0.f, den2 = 0.f, den3 = 0.f;
        float a00=0.f,a01=0.f,a10=0.f,a11=0.f,a20=0.f,a21=0.f,a30=0.f,a31=0.f;

#define GAT_BODY(J)                                                \
    {                                                              \
        int off = lds_off[w][J];                                   \
        float4 ex = lds_ex[w][J];                                  \
        uint u = *(const uint*)(xbase + ((uint)off + lane4));      \
        FMA_MIX_LO(a00, u, ex.x); FMA_MIX_HI(a01, u, ex.x);        \
        FMA_MIX_LO(a10, u, ex.y); FMA_MIX_HI(a11, u, ex.y);        \
        FMA_MIX_LO(a20, u, ex.z); FMA_MIX_HI(a21, u, ex.z);        \
        FMA_MIX_LO(a30, u, ex.w); FMA_MIX_HI(a31, u, ex.w);        \
    }
        for (int e = s0; e < s1; e += 64) {
            const int m = min(64, s1 - e);
            if (lane < m) {
                int src = (int)csr_src[e + lane];
                float4 as = ((const float4*)a_s)[src];
                float v0 = as.x + ad.x; v0 = v0 > 0.f ? v0 : NEG * v0;
                float v1 = as.y + ad.y; v1 = v1 > 0.f ? v1 : NEG * v1;
                float v2 = as.z + ad.z; v2 = v2 > 0.f ? v2 : NEG * v2;
                float v3 = as.w + ad.w; v3 = v3 > 0.f ? v3 : NEG * v3;
                float e0 = __expf(v0); den0 += e0;
                float e1 = __expf(v1); den1 += e1;
                float e2 = __expf(v2); den2 += e2;
                float e3 = __expf(v3); den3 += e3;
                lds_off[w][lane] = src * 256;
                lds_ex[w][lane]  = make_float4(e0, e1, e2, e3);
            }
            asm volatile("s_waitcnt lgkmcnt(0)" ::: "memory");
            int j = 0;
            for (; j + 8 <= m; j += 8) {
                GAT_BODY(j);     GAT_BODY(j + 1); GAT_BODY(j + 2); GAT_BODY(j + 3);
                GAT_BODY(j + 4); GAT_BODY(j + 5); GAT_BODY(j + 6); GAT_BODY(j + 7);
            }
            for (; j < m; ++j) GAT_BODY(j);
            asm volatile("" ::: "memory");
        }
#undef GAT_BODY
#pragma unroll
        for (int m = 32; m >= 1; m >>= 1) {
            den0 += __shfl_xor(den0, m, 64);
            den1 += __shfl_xor(den1, m, 64);
            den2 += __shfl_xor(den2, m, 64);
            den3 += __shfl_xor(den3, m, 64);
        }
        float r0 = 1.f / den0, r1 = 1.f / den1, r2 = 1.f / den2, r3 = 1.f / den3;
        uint* yu = (uint*)&yt[nl][0];
        yu[0 * 64 + lane] = pack2h(a00 * r0, a01 * r0);
        yu[1 * 64 + lane] = pack2h(a10 * r1, a11 * r1);
        yu[2 * 64 + lane] = pack2h(a20 * r2, a21 * r2);
        yu[3 * 64 + lane] = pack2h(a30 * r3, a31 * r3);
    }
    __syncthreads();

    // ---------- Phase B: proj head w: xg[:,64w+c] = ELU(y_w @ Wg_w + bg) ----------
    {
        f16x8 bf[4][4];
#pragma unroll
        for (int ct = 0; ct < 4; ++ct)
#pragma unroll
            for (int ks = 0; ks < 4; ++ks)
                bf[ct][ks] = *(const f16x8*)(wgt + (size_t)(64 * w + 16 * ct + lr) * FIN + ks * 32 + 8 * lg);
        float bgv[4];
#pragma unroll
        for (int ct = 0; ct < 4; ++ct) bgv[ct] = bg[64 * w + 16 * ct + lr];

        f32x4 acc[4];
#pragma unroll
        for (int ct = 0; ct < 4; ++ct) acc[ct] = (f32x4){0.f, 0.f, 0.f, 0.f};
#pragma unroll
        for (int ks = 0; ks < 4; ++ks) {
            f16x8 af = *(const f16x8*)&yt[lr][w * 128 + ks * 32 + 8 * lg];
#pragma unroll
            for (int ct = 0; ct < 4; ++ct)
                acc[ct] = __builtin_amdgcn_mfma_f32_16x16x32_f16(af, bf[ct][ks], acc[ct], 0, 0, 0);
        }
#pragma unroll
        for (int j = 0; j < 4; ++j) {
#pragma unroll
            for (int ct = 0; ct < 4; ++ct) {
                float o = acc[ct][j] + bgv[ct];
                o = o > 0.f ? o : __expf(o) - 1.f;
                xt[4 * lg + j][64 * w + 16 * ct + lr] = __half_as_ushort(__float2half(o));
            }
        }
    }
    __syncthreads();

    // ---------- Phase C: gemm2: xw-tile = xg-tile @ Wc ----------
    {
        f16x8 bf2[2][8];
#pragma unroll
        for (int ct = 0; ct < 2; ++ct)
#pragma unroll
            for (int ks = 0; ks < 8; ++ks)
                bf2[ct][ks] = *(const f16x8*)(wct + (size_t)(32 * w + 16 * ct + lr) * HC + ks * 32 + 8 * lg);

        f32x4 acc2[2];
        acc2[0] = (f32x4){0.f, 0.f, 0.f, 0.f};
        acc2[1] = (f32x4){0.f, 0.f, 0.f, 0.f};
#pragma unroll
        for (int ks = 0; ks < 8; ++ks) {
            f16x8 af = *(const f16x8*)&xt[lr][ks * 32 + 8 * lg];
            acc2[0] = __builtin_amdgcn_mfma_f32_16x16x32_f16(af, bf2[0][ks], acc2[0], 0, 0, 0);
            acc2[1] = __builtin_amdgcn_mfma_f32_16x16x32_f16(af, bf2[1][ks], acc2[1], 0, 0, 0);
        }
#pragma unroll
        for (int j = 0; j < 4; ++j) {
#pragma unroll
            for (int ct = 0; ct < 2; ++ct)
                xt2[4 * lg + j][32 * w + 16 * ct + lr] = __half_as_ushort(__float2half(acc2[ct][j]));
        }
    }
    __syncthreads();

    // coalesced xw store: 16 rows x 128 halfs
    {
        const int rr = t >> 4;
        const int rc = (t & 15) * 8;
        *(uint4*)(xw + (size_t)(rowbase + rr) * HID + rc) = *(const uint4*)&xt2[rr][rc];
    }
}

// ---------------- GCN + classifier head fused ----------------
__global__ __launch_bounds__(256) void gcn_head(const ushort* __restrict__ xw_half,
                                                const int* __restrict__ row_start,
                                                const ushort* __restrict__ csr_src,
                                                const float* __restrict__ dinv,
                                                const float* __restrict__ bc,
                                                const float* __restrict__ Wl,
                                                const float* __restrict__ bl,
                                                float* __restrict__ out) {
    __shared__ int2 lds_ow[4][64];
    const int wid  = threadIdx.x >> 6;
    const int lane = threadIdx.x & 63;
    const int node = blockIdx.x * 4 + wid;
    if (node >= NN) return;
    const int s0 = row_start[node], s1 = row_start[node + 1];
    const float di = dinv[node];
    float ax = 0.f, ay = 0.f;
    const char* xwbase = (const char*)xw_half;
    const uint lane4 = (uint)lane * 4;

#define GCN_BODY(OW)                                            \
    {                                                           \
        uint v = *(const uint*)(xwbase + ((uint)(OW).x + lane4)); \
        float ww = __int_as_float((OW).y);                      \
        FMA_MIX_LO(ax, v, ww); FMA_MIX_HI(ay, v, ww);           \
    }

    for (int e = s0; e < s1; e += 64) {
        const int m = min(64, s1 - e);
        if (lane < m) {
            int s = (int)csr_src[e + lane];
            lds_ow[wid][lane] = make_int2(s * 256, __float_as_int(dinv[s] * di));
        }
        asm volatile("s_waitcnt lgkmcnt(0)" ::: "memory");
        int j = 0;
        for (; j + 8 <= m; j += 8) {
            int2 ow0 = lds_ow[wid][j];
            int2 ow1 = lds_ow[wid][j + 1];
            int2 ow2 = lds_ow[wid][j + 2];
            int2 ow3 = lds_ow[wid][j + 3];
            int2 ow4 = lds_ow[wid][j + 4];
            int2 ow5 = lds_ow[wid][j + 5];
            int2 ow6 = lds_ow[wid][j + 6];
            int2 ow7 = lds_ow[wid][j + 7];
            GCN_BODY(ow0); GCN_BODY(ow1); GCN_BODY(ow2); GCN_BODY(ow3);
            GCN_BODY(ow4); GCN_BODY(ow5); GCN_BODY(ow6); GCN_BODY(ow7);
        }
        for (; j + 4 <= m; j += 4) {
            int2 ow0 = lds_ow[wid][j];
            int2 ow1 = lds_ow[wid][j + 1];
            int2 ow2 = lds_ow[wid][j + 2];
            int2 ow3 = lds_ow[wid][j + 3];
            GCN_BODY(ow0); GCN_BODY(ow1); GCN_BODY(ow2); GCN_BODY(ow3);
        }
        for (; j < m; ++j) {
            int2 ow = lds_ow[wid][j];
            GCN_BODY(ow);
        }
        asm volatile("" ::: "memory");
    }
#undef GCN_BODY
    float2 b = ((const float2*)bc)[lane];
    float o0 = ax + b.x; o0 = o0 > 0.f ? o0 : 0.f;
    float o1 = ay + b.y; o1 = o1 > 0.f ? o1 : 0.f;

    float p[NCLS];
#pragma unroll
    for (int j = 0; j < NCLS; ++j)
        p[j] = o0 * Wl[(2 * lane) * NCLS + j] + o1 * Wl[(2 * lane + 1) * NCLS + j];
#pragma unroll
    for (int m = 32; m >= 1; m >>= 1) {
#pragma unroll
        for (int j = 0; j < NCLS; ++j) p[j] += __shfl_xor(p[j], m, 64);
    }
#pragma unroll
    for (int j = 0; j < NCLS; ++j) p[j] += bl[j];
    float mx = p[0];
#pragma unroll
    for (int j = 1; j < NCLS; ++j) mx = fmaxf(mx, p[j]);
    float s = 0.f;
#pragma unroll
    for (int j = 0; j < NCLS; ++j) s += __expf(p[j] - mx);
    float ls = __logf(s);
    if (lane == 0) {
#pragma unroll
        for (int j = 0; j < NCLS; ++j) out[(size_t)node * NCLS + j] = p[j] - mx - ls;
    }
}

extern "C" void kernel_launch(void* const* d_in, const int* in_sizes, int n_in,
                              void* d_out, int out_size, void* d_ws, size_t ws_size,
                              hipStream_t stream) {
    const float* x       = (const float*)d_in[0];
    const float* Wg      = (const float*)d_in[2];
    const float* att_src = (const float*)d_in[3];
    const float* att_dst = (const float*)d_in[4];
    const float* bg      = (const float*)d_in[5];
    const float* Wc      = (const float*)d_in[6];
    const float* bc      = (const float*)d_in[7];
    const float* Wl      = (const float*)d_in[8];
    const float* bl      = (const float*)d_in[9];
    const int*   ei      = (const int*)d_in[10];
    float* out = (float*)d_out;

    char* p = (char*)d_ws;
    auto alloc = [&](size_t bytes) -> void* {
        void* r = (void*)p;
        p += (bytes + 255) & ~(size_t)255;
        return r;
    };
    ushort* x_half    = (ushort*)alloc((size_t)NN * FIN * 2);   // 12.8 MB
    ushort* xw_half   = (ushort*)alloc((size_t)NN * HID * 2);   // 12.8 MB (separate: read+write same kernel)
    float*  a_s       = (float*)alloc((size_t)NN * 4 * 4);
    float*  a_d       = (float*)alloc((size_t)NN * 4 * 4);
    float*  dinv      = (float*)alloc((size_t)NN * 4);
    int*    row_start = (int*)alloc((size_t)(NN + 1) * 4);
    ushort* csr_src   = (ushort*)alloc((size_t)E2 * 2);
    uint*   ebuf      = (uint*)alloc((size_t)E2 * 4);
    uint*   blockhist = (uint*)alloc((size_t)NB2 * NBLK * 4);
    uint*   blockoff  = (uint*)alloc((size_t)NB2 * NBLK * 4);
    uint*   total     = (uint*)alloc(256 * 4);
    ushort* wgt       = (ushort*)alloc((size_t)HC * FIN * 2);
    ushort* wct       = (ushort*)alloc((size_t)HID * HC * 2);
    float4* vs        = (float4*)alloc(FIN * 16);
    float4* vd        = (float4*)alloc(FIN * 16);

    prep_kernel<<<128, 256, 0, stream>>>(Wg, Wc, att_src, att_dst, wgt, wct, vs, vd);
    prep_x<<<(NN + 3) / 4, 256, 0, stream>>>(x, vs, vd, x_half, a_s, a_d);

    hist_coarse<<<NBLK, 256, 0, stream>>>(ei, blockhist);
    scan_blocks<<<NB2, 256, 0, stream>>>(blockhist, blockoff, total);
    reorder_kernel<<<NBLK, 256, 0, stream>>>(ei, blockoff, total, ebuf);
    bucket_csr<<<NB2, 256, 0, stream>>>(ebuf, total, row_start, dinv, csr_src);

    gat_fused<<<NN / 16, 256, 0, stream>>>(x_half, a_s, a_d, row_start, csr_src,
                                           wgt, bg, wct, xw_half);
    gcn_head<<<(NN + 3) / 4, 256, 0, stream>>>(xw_half, row_start, csr_src, dinv, bc, Wl, bl, out);
}

// Round 13
// 190.936 us; speedup vs baseline: 1.1369x; 1.1369x over previous
//
#include <hip/hip_runtime.h>
#include <hip/hip_fp16.h>
#include <math.h>

#define NN 50000
#define EE 800000
#define E2 (EE + NN)
#define FIN 128
#define HC 256
#define HID 128
#define NCLS 10
#define NEG 0.2f
#define NB2 196          // buckets of 256 nodes
#define NBLK 256         // edge-partition blocks
#define WPART ((E2 + NBLK - 1) / NBLK)

typedef _Float16 f16x8 __attribute__((ext_vector_type(8)));
typedef float f32x4 __attribute__((ext_vector_type(4)));

#define FMA_MIX_LO(acc, u, w) \
    asm("v_fma_mix_f32 %0, %1, %2, %0 op_sel:[0,0,0] op_sel_hi:[1,0,0]" \
        : "+v"(acc) : "v"(u), "v"(w))
#define FMA_MIX_HI(acc, u, w) \
    asm("v_fma_mix_f32 %0, %1, %2, %0 op_sel:[1,0,0] op_sel_hi:[1,0,0]" \
        : "+v"(acc) : "v"(u), "v"(w))

__device__ inline uint pack2h(float a, float b) {
    return (uint)__half_as_ushort(__float2half(a)) |
           ((uint)__half_as_ushort(__float2half(b)) << 16);
}

// ---- prep: wgt[256][128], wct[128][256] fp16 transposed; vs/vd[128] float4 (folded att) ----
__global__ __launch_bounds__(256) void prep_kernel(const float* __restrict__ Wg,
                                                   const float* __restrict__ Wc,
                                                   const float* __restrict__ att_s,
                                                   const float* __restrict__ att_d,
                                                   ushort* __restrict__ wgt,
                                                   ushort* __restrict__ wct,
                                                   float4* __restrict__ vs,
                                                   float4* __restrict__ vd) {
    int i = blockIdx.x * 256 + threadIdx.x;
    if (i < HC * FIN) {
        int c = i & 255, k = i >> 8;
        wgt[c * FIN + k] = __half_as_ushort(__float2half(Wg[i]));
        int c2 = i & 127, k2 = i >> 7;
        wct[c2 * HC + k2] = __half_as_ushort(__float2half(Wc[i]));
    }
    if (blockIdx.x == 0 && threadIdx.x < FIN) {
        int k = threadIdx.x;
        float s[4] = {0.f, 0.f, 0.f, 0.f}, d[4] = {0.f, 0.f, 0.f, 0.f};
        for (int h = 0; h < 4; ++h)
            for (int c = 0; c < 64; ++c) {
                float wv = Wg[k * HC + h * 64 + c];
                s[h] += wv * att_s[h * 64 + c];
                d[h] += wv * att_d[h * 64 + c];
            }
        vs[k] = make_float4(s[0], s[1], s[2], s[3]);
        vd[k] = make_float4(d[0], d[1], d[2], d[3]);
    }
}

// ---- prep_x: x -> fp16 cast + a_s/a_d = x @ vs/vd ----
__global__ __launch_bounds__(256) void prep_x(const float* __restrict__ x,
                                              const float4* __restrict__ vs,
                                              const float4* __restrict__ vd,
                                              ushort* __restrict__ x_half,
                                              float* __restrict__ a_s,
                                              float* __restrict__ a_d) {
    const int node = blockIdx.x * 4 + (threadIdx.x >> 6);
    const int lane = threadIdx.x & 63;
    if (node >= NN) return;
    float2 xv = ((const float2*)(x + (size_t)node * FIN))[lane];
    ((uint*)x_half)[(size_t)node * 64 + lane] = pack2h(xv.x, xv.y);
    float4 v0 = vs[2 * lane], v1 = vs[2 * lane + 1];
    float4 d0 = vd[2 * lane], d1 = vd[2 * lane + 1];
    float ps0 = xv.x * v0.x + xv.y * v1.x;
    float ps1 = xv.x * v0.y + xv.y * v1.y;
    float ps2 = xv.x * v0.z + xv.y * v1.z;
    float ps3 = xv.x * v0.w + xv.y * v1.w;
    float pd0 = xv.x * d0.x + xv.y * d1.x;
    float pd1 = xv.x * d0.y + xv.y * d1.y;
    float pd2 = xv.x * d0.z + xv.y * d1.z;
    float pd3 = xv.x * d0.w + xv.y * d1.w;
#pragma unroll
    for (int m = 32; m >= 1; m >>= 1) {
        ps0 += __shfl_xor(ps0, m, 64); ps1 += __shfl_xor(ps1, m, 64);
        ps2 += __shfl_xor(ps2, m, 64); ps3 += __shfl_xor(ps3, m, 64);
        pd0 += __shfl_xor(pd0, m, 64); pd1 += __shfl_xor(pd1, m, 64);
        pd2 += __shfl_xor(pd2, m, 64); pd3 += __shfl_xor(pd3, m, 64);
    }
    if (lane == 0) {
        ((float4*)a_s)[node] = make_float4(ps0, ps1, ps2, ps3);
        ((float4*)a_d)[node] = make_float4(pd0, pd1, pd2, pd3);
    }
}

// ================= CSR build: bucketed, no global atomics =================
__global__ __launch_bounds__(256) void hist_coarse(const int* __restrict__ ei,
                                                   uint* __restrict__ blockhist) {
    __shared__ uint h[NB2];
    for (int i = threadIdx.x; i < NB2; i += 256) h[i] = 0;
    __syncthreads();
    int e0 = blockIdx.x * WPART, e1 = min(E2, e0 + WPART);
    for (int e = e0 + threadIdx.x; e < e1; e += 256) {
        int dst = (e < EE) ? ei[EE + e] : e - EE;
        atomicAdd(&h[dst >> 8], 1u);
    }
    __syncthreads();
    for (int i = threadIdx.x; i < NB2; i += 256) blockhist[i * NBLK + blockIdx.x] = h[i];
}

__global__ __launch_bounds__(256) void scan_blocks(const uint* __restrict__ blockhist,
                                                   uint* __restrict__ blockoff,
                                                   uint* __restrict__ total) {
    __shared__ uint sh[256];
    int b = blockIdx.x, t = threadIdx.x;
    uint v = blockhist[b * NBLK + t];
    sh[t] = v;
    __syncthreads();
#pragma unroll
    for (int off = 1; off < 256; off <<= 1) {
        uint y = (t >= off) ? sh[t - off] : 0;
        __syncthreads();
        sh[t] += y;
        __syncthreads();
    }
    blockoff[b * NBLK + t] = sh[t] - v;
    if (t == 255) total[b] = sh[255];
}

// reorder: local scan of total[] gives bucket bases
__global__ __launch_bounds__(256) void reorder_kernel(const int* __restrict__ ei,
                                                      const uint* __restrict__ blockoff,
                                                      const uint* __restrict__ total,
                                                      uint* __restrict__ ebuf) {
    __shared__ uint sh[256];
    __shared__ uint cur[NB2];
    int t = threadIdx.x;
    uint v = (t < NB2) ? total[t] : 0;
    sh[t] = v;
    __syncthreads();
#pragma unroll
    for (int off = 1; off < 256; off <<= 1) {
        uint y = (t >= off) ? sh[t - off] : 0;
        __syncthreads();
        sh[t] += y;
        __syncthreads();
    }
    if (t < NB2) cur[t] = (sh[t] - v) + blockoff[t * NBLK + blockIdx.x];
    __syncthreads();
    int e0 = blockIdx.x * WPART, e1 = min(E2, e0 + WPART);
    for (int e = e0 + t; e < e1; e += 256) {
        int src, dst;
        if (e < EE) { src = ei[e]; dst = ei[EE + e]; }
        else        { src = dst = e - EE; }
        uint p = atomicAdd(&cur[dst >> 8], 1u);
        ebuf[p] = (uint)src | ((uint)(dst & 255) << 16);
    }
}

// per-bucket finalize
__global__ __launch_bounds__(256) void bucket_csr(const uint* __restrict__ ebuf,
                                                  const uint* __restrict__ total,
                                                  int* __restrict__ row_start,
                                                  float* __restrict__ dinv,
                                                  ushort* __restrict__ csr_src) {
    __shared__ uint ldeg[256], lcur[256], sh[256];
    __shared__ uint sbe[2];
    const int b = blockIdx.x, t = threadIdx.x;
    uint v = (t < NB2) ? total[t] : 0;
    sh[t] = v;
    __syncthreads();
#pragma unroll
    for (int off = 1; off < 256; off <<= 1) {
        uint y = (t >= off) ? sh[t - off] : 0;
        __syncthreads();
        sh[t] += y;
        __syncthreads();
    }
    if (t == b) { sbe[0] = sh[t] - v; sbe[1] = sh[t]; }
    ldeg[t] = 0;
    __syncthreads();
    const uint base = sbe[0], end = sbe[1];
    for (uint i = base + t; i < end; i += 256) atomicAdd(&ldeg[ebuf[i] >> 16], 1u);
    __syncthreads();
    uint dv = ldeg[t];
    sh[t] = dv;
    __syncthreads();
#pragma unroll
    for (int off = 1; off < 256; off <<= 1) {
        uint y = (t >= off) ? sh[t - off] : 0;
        __syncthreads();
        sh[t] += y;
        __syncthreads();
    }
    uint lscan = sh[t] - dv;
    int node = b * 256 + t;
    if (node < NN) {
        row_start[node] = (int)(base + lscan);
        dinv[node] = rsqrtf((float)dv);
    }
    lcur[t] = base + lscan;
    __syncthreads();
    for (uint i = base + t; i < end; i += 256) {
        uint pk = ebuf[i];
        uint p = atomicAdd(&lcur[pk >> 16], 1u);
        csr_src[p] = (ushort)(pk & 0xFFFFu);
    }
    if (b == 0 && t == 0) row_start[NN] = E2;
}

// ---- fused GAT on x: gather x_half[src] (256B rows), 4-head weighted sums -> y[N,4,128] ----
__global__ __launch_bounds__(256) void gat_x(const ushort* __restrict__ x_half,
                                             const float* __restrict__ a_s,
                                             const float* __restrict__ a_d,
                                             const int* __restrict__ row_start,
                                             const ushort* __restrict__ csr_src,
                                             ushort* __restrict__ y) {
    __shared__ int    lds_off[4][64];
    __shared__ float4 lds_ex[4][64];
    const int wid  = threadIdx.x >> 6;
    const int lane = threadIdx.x & 63;
    const int node = blockIdx.x * 4 + wid;
    if (node >= NN) return;
    const int s0 = row_start[node], s1 = row_start[node + 1];
    const float4 ad = ((const float4*)a_d)[node];

    float den0 = 0.f, den1 = 0.f, den2 = 0.f, den3 = 0.f;
    float a00=0.f,a01=0.f,a10=0.f,a11=0.f,a20=0.f,a21=0.f,a30=0.f,a31=0.f;
    const char* xbase = (const char*)x_half;
    const uint lane4 = (uint)lane * 4;

#define GAT_BODY(J)                                                \
    {                                                              \
        int off = lds_off[wid][J];                                 \
        float4 ex = lds_ex[wid][J];                                \
        uint u = *(const uint*)(xbase + ((uint)off + lane4));      \
        FMA_MIX_LO(a00, u, ex.x); FMA_MIX_HI(a01, u, ex.x);        \
        FMA_MIX_LO(a10, u, ex.y); FMA_MIX_HI(a11, u, ex.y);        \
        FMA_MIX_LO(a20, u, ex.z); FMA_MIX_HI(a21, u, ex.z);        \
        FMA_MIX_LO(a30, u, ex.w); FMA_MIX_HI(a31, u, ex.w);        \
    }

    for (int e = s0; e < s1; e += 64) {
        const int m = min(64, s1 - e);
        if (lane < m) {
            int src = (int)csr_src[e + lane];
            float4 as = ((const float4*)a_s)[src];
            float v0 = as.x + ad.x; v0 = v0 > 0.f ? v0 : NEG * v0;
            float v1 = as.y + ad.y; v1 = v1 > 0.f ? v1 : NEG * v1;
            float v2 = as.z + ad.z; v2 = v2 > 0.f ? v2 : NEG * v2;
            float v3 = as.w + ad.w; v3 = v3 > 0.f ? v3 : NEG * v3;
            float e0 = __expf(v0); den0 += e0;
            float e1 = __expf(v1); den1 += e1;
            float e2 = __expf(v2); den2 += e2;
            float e3 = __expf(v3); den3 += e3;
            lds_off[wid][lane] = src * 256;
            lds_ex[wid][lane]  = make_float4(e0, e1, e2, e3);
        }
        asm volatile("s_waitcnt lgkmcnt(0)" ::: "memory");
        int j = 0;
        for (; j + 8 <= m; j += 8) {
            GAT_BODY(j);     GAT_BODY(j + 1); GAT_BODY(j + 2); GAT_BODY(j + 3);
            GAT_BODY(j + 4); GAT_BODY(j + 5); GAT_BODY(j + 6); GAT_BODY(j + 7);
        }
        for (; j < m; ++j) GAT_BODY(j);
        asm volatile("" ::: "memory");
    }
#undef GAT_BODY
#pragma unroll
    for (int m = 32; m >= 1; m >>= 1) {
        den0 += __shfl_xor(den0, m, 64);
        den1 += __shfl_xor(den1, m, 64);
        den2 += __shfl_xor(den2, m, 64);
        den3 += __shfl_xor(den3, m, 64);
    }
    float r0 = 1.f / den0, r1 = 1.f / den1, r2 = 1.f / den2, r3 = 1.f / den3;
    uint* yrow = (uint*)y + (size_t)node * 256;
    yrow[0 * 64 + lane] = pack2h(a00 * r0, a01 * r0);
    yrow[1 * 64 + lane] = pack2h(a10 * r1, a11 * r1);
    yrow[2 * 64 + lane] = pack2h(a20 * r2, a21 * r2);
    yrow[3 * 64 + lane] = pack2h(a30 * r3, a31 * r3);
}

// ==== fused dense: proj (y @ Wg + bg -> ELU -> xg LDS) then gemm2 (xg @ Wc -> xw) ====
__global__ __launch_bounds__(256) void proj_gemm2(const ushort* __restrict__ y,
                                                  const ushort* __restrict__ wgt,
                                                  const float* __restrict__ bg,
                                                  const ushort* __restrict__ wct,
                                                  ushort* __restrict__ xw) {
    __shared__ ushort xt[16][264];    // xg-tile (ELU'd)
    __shared__ ushort xt2[16][136];   // xw-tile staging
    const int t = threadIdx.x;
    const int w  = t >> 6;
    const int l  = t & 63;
    const int lr = l & 15;
    const int lg = l >> 4;
    const int rr = t >> 4;
    const int rc = (t & 15) * 8;

    // B-fragments for proj (head w) and gemm2 (cols 32w..32w+31)
    f16x8 bf[4][4];
#pragma unroll
    for (int ct = 0; ct < 4; ++ct)
#pragma unroll
        for (int ks = 0; ks < 4; ++ks)
            bf[ct][ks] = *(const f16x8*)(wgt + (size_t)(64 * w + 16 * ct + lr) * FIN + ks * 32 + 8 * lg);
    float bgv[4];
#pragma unroll
    for (int ct = 0; ct < 4; ++ct) bgv[ct] = bg[64 * w + 16 * ct + lr];

    f16x8 bf2[2][8];
#pragma unroll
    for (int ct = 0; ct < 2; ++ct)
#pragma unroll
        for (int ks = 0; ks < 8; ++ks)
            bf2[ct][ks] = *(const f16x8*)(wct + (size_t)(32 * w + 16 * ct + lr) * HC + ks * 32 + 8 * lg);

    for (int rt = blockIdx.x; rt < 3125; rt += gridDim.x) {
        const int r0 = rt * 16;
        // Phase B: proj head w
        f32x4 acc[4];
#pragma unroll
        for (int ct = 0; ct < 4; ++ct) acc[ct] = (f32x4){0.f, 0.f, 0.f, 0.f};
#pragma unroll
        for (int ks = 0; ks < 4; ++ks) {
            f16x8 af = *(const f16x8*)(y + (size_t)(r0 + lr) * 512 + w * 128 + ks * 32 + 8 * lg);
#pragma unroll
            for (int ct = 0; ct < 4; ++ct)
                acc[ct] = __builtin_amdgcn_mfma_f32_16x16x32_f16(af, bf[ct][ks], acc[ct], 0, 0, 0);
        }
#pragma unroll
        for (int j = 0; j < 4; ++j) {
#pragma unroll
            for (int ct = 0; ct < 4; ++ct) {
                float o = acc[ct][j] + bgv[ct];
                o = o > 0.f ? o : __expf(o) - 1.f;
                xt[4 * lg + j][64 * w + 16 * ct + lr] = __half_as_ushort(__float2half(o));
            }
        }
        __syncthreads();
        // Phase C: gemm2 on the LDS tile
        f32x4 acc2[2];
        acc2[0] = (f32x4){0.f, 0.f, 0.f, 0.f};
        acc2[1] = (f32x4){0.f, 0.f, 0.f, 0.f};
#pragma unroll
        for (int ks = 0; ks < 8; ++ks) {
            f16x8 af = *(const f16x8*)&xt[lr][ks * 32 + 8 * lg];
            acc2[0] = __builtin_amdgcn_mfma_f32_16x16x32_f16(af, bf2[0][ks], acc2[0], 0, 0, 0);
            acc2[1] = __builtin_amdgcn_mfma_f32_16x16x32_f16(af, bf2[1][ks], acc2[1], 0, 0, 0);
        }
#pragma unroll
        for (int j = 0; j < 4; ++j) {
#pragma unroll
            for (int ct = 0; ct < 2; ++ct)
                xt2[4 * lg + j][32 * w + 16 * ct + lr] = __half_as_ushort(__float2half(acc2[ct][j]));
        }
        __syncthreads();
        *(uint4*)(xw + (size_t)(r0 + rr) * HID + rc) = *(const uint4*)&xt2[rr][rc];
        __syncthreads();
    }
}

// ---------------- GCN + classifier head fused ----------------
__global__ __launch_bounds__(256) void gcn_head(const ushort* __restrict__ xw_half,
                                                const int* __restrict__ row_start,
                                                const ushort* __restrict__ csr_src,
                                                const float* __restrict__ dinv,
                                                const float* __restrict__ bc,
                                                const float* __restrict__ Wl,
                                                const float* __restrict__ bl,
                                                float* __restrict__ out) {
    __shared__ int2 lds_ow[4][64];
    const int wid  = threadIdx.x >> 6;
    const int lane = threadIdx.x & 63;
    const int node = blockIdx.x * 4 + wid;
    if (node >= NN) return;
    const int s0 = row_start[node], s1 = row_start[node + 1];
    const float di = dinv[node];
    float ax = 0.f, ay = 0.f;
    const char* xwbase = (const char*)xw_half;
    const uint lane4 = (uint)lane * 4;

#define GCN_BODY(OW)                                            \
    {                                                           \
        uint v = *(const uint*)(xwbase + ((uint)(OW).x + lane4)); \
        float ww = __int_as_float((OW).y);                      \
        FMA_MIX_LO(ax, v, ww); FMA_MIX_HI(ay, v, ww);           \
    }

    for (int e = s0; e < s1; e += 64) {
        const int m = min(64, s1 - e);
        if (lane < m) {
            int s = (int)csr_src[e + lane];
            lds_ow[wid][lane] = make_int2(s * 256, __float_as_int(dinv[s] * di));
        }
        asm volatile("s_waitcnt lgkmcnt(0)" ::: "memory");
        int j = 0;
        for (; j + 8 <= m; j += 8) {
            int2 ow0 = lds_ow[wid][j];
            int2 ow1 = lds_ow[wid][j + 1];
            int2 ow2 = lds_ow[wid][j + 2];
            int2 ow3 = lds_ow[wid][j + 3];
            int2 ow4 = lds_ow[wid][j + 4];
            int2 ow5 = lds_ow[wid][j + 5];
            int2 ow6 = lds_ow[wid][j + 6];
            int2 ow7 = lds_ow[wid][j + 7];
            GCN_BODY(ow0); GCN_BODY(ow1); GCN_BODY(ow2); GCN_BODY(ow3);
            GCN_BODY(ow4); GCN_BODY(ow5); GCN_BODY(ow6); GCN_BODY(ow7);
        }
        for (; j + 4 <= m; j += 4) {
            int2 ow0 = lds_ow[wid][j];
            int2 ow1 = lds_ow[wid][j + 1];
            int2 ow2 = lds_ow[wid][j + 2];
            int2 ow3 = lds_ow[wid][j + 3];
            GCN_BODY(ow0); GCN_BODY(ow1); GCN_BODY(ow2); GCN_BODY(ow3);
        }
        for (; j < m; ++j) {
            int2 ow = lds_ow[wid][j];
            GCN_BODY(ow);
        }
        asm volatile("" ::: "memory");
    }
#undef GCN_BODY
    float2 b = ((const float2*)bc)[lane];
    float o0 = ax + b.x; o0 = o0 > 0.f ? o0 : 0.f;
    float o1 = ay + b.y; o1 = o1 > 0.f ? o1 : 0.f;

    float p[NCLS];
#pragma unroll
    for (int j = 0; j < NCLS; ++j)
        p[j] = o0 * Wl[(2 * lane) * NCLS + j] + o1 * Wl[(2 * lane + 1) * NCLS + j];
#pragma unroll
    for (int m = 32; m >= 1; m >>= 1) {
#pragma unroll
        for (int j = 0; j < NCLS; ++j) p[j] += __shfl_xor(p[j], m, 64);
    }
#pragma unroll
    for (int j = 0; j < NCLS; ++j) p[j] += bl[j];
    float mx = p[0];
#pragma unroll
    for (int j = 1; j < NCLS; ++j) mx = fmaxf(mx, p[j]);
    float s = 0.f;
#pragma unroll
    for (int j = 0; j < NCLS; ++j) s += __expf(p[j] - mx);
    float ls = __logf(s);
    if (lane == 0) {
#pragma unroll
        for (int j = 0; j < NCLS; ++j) out[(size_t)node * NCLS + j] = p[j] - mx - ls;
    }
}

extern "C" void kernel_launch(void* const* d_in, const int* in_sizes, int n_in,
                              void* d_out, int out_size, void* d_ws, size_t ws_size,
                              hipStream_t stream) {
    const float* x       = (const float*)d_in[0];
    const float* Wg      = (const float*)d_in[2];
    const float* att_src = (const float*)d_in[3];
    const float* att_dst = (const float*)d_in[4];
    const float* bg      = (const float*)d_in[5];
    const float* Wc      = (const float*)d_in[6];
    const float* bc      = (const float*)d_in[7];
    const float* Wl      = (const float*)d_in[8];
    const float* bl      = (const float*)d_in[9];
    const int*   ei      = (const int*)d_in[10];
    float* out = (float*)d_out;

    char* p = (char*)d_ws;
    auto alloc = [&](size_t bytes) -> void* {
        void* r = (void*)p;
        p += (bytes + 255) & ~(size_t)255;
        return r;
    };
    ushort* x_half    = (ushort*)alloc((size_t)NN * FIN * 2);   // 12.8 MB
    ushort* y         = (ushort*)alloc((size_t)NN * 512 * 2);   // 51.2 MB
    ushort* xw_half   = (ushort*)alloc((size_t)NN * HID * 2);   // 12.8 MB
    float*  a_s       = (float*)alloc((size_t)NN * 4 * 4);
    float*  a_d       = (float*)alloc((size_t)NN * 4 * 4);
    float*  dinv      = (float*)alloc((size_t)NN * 4);
    int*    row_start = (int*)alloc((size_t)(NN + 1) * 4);
    ushort* csr_src   = (ushort*)alloc((size_t)E2 * 2);
    uint*   ebuf      = (uint*)alloc((size_t)E2 * 4);
    uint*   blockhist = (uint*)alloc((size_t)NB2 * NBLK * 4);
    uint*   blockoff  = (uint*)alloc((size_t)NB2 * NBLK * 4);
    uint*   total     = (uint*)alloc(256 * 4);
    ushort* wgt       = (ushort*)alloc((size_t)HC * FIN * 2);
    ushort* wct       = (ushort*)alloc((size_t)HID * HC * 2);
    float4* vs        = (float4*)alloc(FIN * 16);
    float4* vd        = (float4*)alloc(FIN * 16);

    prep_kernel<<<128, 256, 0, stream>>>(Wg, Wc, att_src, att_dst, wgt, wct, vs, vd);
    prep_x<<<(NN + 3) / 4, 256, 0, stream>>>(x, vs, vd, x_half, a_s, a_d);

    hist_coarse<<<NBLK, 256, 0, stream>>>(ei, blockhist);
    scan_blocks<<<NB2, 256, 0, stream>>>(blockhist, blockoff, total);
    reorder_kernel<<<NBLK, 256, 0, stream>>>(ei, blockoff, total, ebuf);
    bucket_csr<<<NB2, 256, 0, stream>>>(ebuf, total, row_start, dinv, csr_src);

    gat_x<<<(NN + 3) / 4, 256, 0, stream>>>(x_half, a_s, a_d, row_start, csr_src, y);
    proj_gemm2<<<1250, 256, 0, stream>>>(y, wgt, bg, wct, xw_half);
    gcn_head<<<(NN + 3) / 4, 256, 0, stream>>>(xw_half, row_start, csr_src, dinv, bc, Wl, bl, out);
}